// Round 4
// baseline (25.142 us; speedup 1.0000x reference)
//
#include <hip/hip_runtime.h>

// Problem constants (fixed by setup_inputs shapes)
#define HOUT 39
#define WOUT 39
#define COUT 64
#define HIN  160
#define WIN  160
#define CIN  4
#define F    8
#define S    4
#define TI   40   // output tiles per side (160/4)

// Tile-gather formulation: block owns a 4x4x4 output tile. Only conv positions
// (i,j) in {I-1,I}x{J-1,J} can scatter into this tile. Each wave takes a
// 64-wide k-segment (so w is read ONCE per block, coalesced over lane=c) and
// computes partial argmax for all 4 candidate pairs. LDS merge in ascending-k
// order (strict >, first-occurrence ties like jnp.argmax), then winners inside
// the tile accumulate via LDS atomics and the tile is stored directly.
// No memset node, no global atomics, every output element written exactly once.
__global__ __launch_bounds__(256) void argmax_rel_tile(
    const float* __restrict__ rel,   // [39,39,64]
    const float* __restrict__ x,     // [160,160,4]
    const float* __restrict__ w,     // [8,8,4,64] flat: [k][c]
    float* __restrict__ out)         // [160,160,4]
{
    const int I  = blockIdx.x / TI;
    const int J  = blockIdx.x % TI;
    const int wv = threadIdx.x >> 6;   // k-segment 0..3
    const int c  = threadIdx.x & 63;   // output channel

    __shared__ float pm[4][4][COUT];   // [kseg][pair][c] partial max
    __shared__ int   pa[4][4][COUT];   // partial arg
    __shared__ float acc[64];          // tile accumulator [lx][ly][pc]

    if (threadIdx.x < 64) acc[threadIdx.x] = 0.0f;

    // Candidate conv positions (wave-uniform): pair p -> (I-1+(p>>1), J-1+(p&1))
    int  ic[4], jc[4];
    bool vld[4];
    #pragma unroll
    for (int p = 0; p < 4; ++p) {
        const int i = I - 1 + (p >> 1);
        const int j = J - 1 + (p & 1);
        vld[p] = (i >= 0) && (i < HOUT) && (j >= 0) && (j < WOUT);
        ic[p]  = i < 0 ? 0 : (i > HOUT - 1 ? HOUT - 1 : i);   // clamp (guarded later)
        jc[p]  = j < 0 ? 0 : (j > WOUT - 1 ? WOUT - 1 : j);
    }

    const int kb = wv * 64;            // k window [kb, kb+64): patch rows 2wv, 2wv+1

    float m[4][2];                     // [pair][rr] -- fully unrolled, static idx
    int   a[4][2];
    #pragma unroll
    for (int p = 0; p < 4; ++p) {
        #pragma unroll
        for (int rr = 0; rr < 2; ++rr) { m[p][rr] = -__builtin_inff(); a[p][rr] = kb + 32 * rr; }
    }

    #pragma unroll
    for (int rr = 0; rr < 2; ++rr) {
        const int px = 2 * wv + rr;    // patch row
        // 32 consecutive floats per pair: columns 4j..4j+7, channels 0..3
        const float* xr0 = x + ((S * ic[0] + px) * WIN + S * jc[0]) * CIN;
        const float* xr1 = x + ((S * ic[1] + px) * WIN + S * jc[1]) * CIN;
        const float* xr2 = x + ((S * ic[2] + px) * WIN + S * jc[2]) * CIN;
        const float* xr3 = x + ((S * ic[3] + px) * WIN + S * jc[3]) * CIN;
        const float* wp  = w + (kb + 32 * rr) * COUT + c;   // coalesced over lanes
        #pragma unroll
        for (int t = 0; t < 32; ++t) {
            const float wval = wp[t * COUT];   // one w read feeds 4 pairs
            const float p0 = xr0[t] * wval;    // x reads wave-uniform (broadcast)
            const float p1 = xr1[t] * wval;
            const float p2 = xr2[t] * wval;
            const float p3 = xr3[t] * wval;
            const int   k  = kb + 32 * rr + t;
            if (p0 > m[0][rr]) { m[0][rr] = p0; a[0][rr] = k; }
            if (p1 > m[1][rr]) { m[1][rr] = p1; a[1][rr] = k; }
            if (p2 > m[2][rr]) { m[2][rr] = p2; a[2][rr] = k; }
            if (p3 > m[3][rr]) { m[3][rr] = p3; a[3][rr] = k; }
        }
    }

    // intra-wave merge of the two 32-chains (ascending k, strict >)
    #pragma unroll
    for (int p = 0; p < 4; ++p) {
        float mp = m[p][0]; int ap = a[p][0];
        if (m[p][1] > mp) { mp = m[p][1]; ap = a[p][1]; }
        pm[wv][p][c] = mp;
        pa[wv][p][c] = ap;
    }
    __syncthreads();

    // cross-wave merge: thread (pf, cf) finalizes pair pf, channel cf
    {
        const int pf = threadIdx.x >> 6;
        const int cf = c;
        float bm = pm[0][pf][cf]; int ba = pa[0][pf][cf];
        #pragma unroll
        for (int s = 1; s < 4; ++s) {            // ascending k segments
            const float sm = pm[s][pf][cf];
            if (sm > bm) { bm = sm; ba = pa[s][pf][cf]; }
        }
        if (vld[pf]) {
            const int px_ = ba >> 5;             // patch row
            const int rem = ba & 31;             // py*4+pc
            const int gx  = S * ic[pf] + px_;
            const int gy  = S * jc[pf] + (rem >> 2);
            const int pc  = rem & 3;
            const int lx  = gx - 4 * I;
            const int ly  = gy - 4 * J;
            if (lx >= 0 && lx < 4 && ly >= 0 && ly < 4) {
                atomicAdd(&acc[lx * 16 + ly * 4 + pc],
                          rel[(ic[pf] * WOUT + jc[pf]) * COUT + cf]);
            }
        }
    }
    __syncthreads();

    // store the owned tile: row r = lx, off = ly*4+pc (16 consecutive floats/row)
    if (threadIdx.x < 64) {
        const int r   = threadIdx.x >> 4;
        const int off = threadIdx.x & 15;
        out[(4 * I + r) * (WIN * CIN) + (4 * J) * CIN + off] = acc[threadIdx.x];
    }
}

extern "C" void kernel_launch(void* const* d_in, const int* in_sizes, int n_in,
                              void* d_out, int out_size, void* d_ws, size_t ws_size,
                              hipStream_t stream) {
    const float* rel = (const float*)d_in[0];   // [1,39,39,64]
    const float* x   = (const float*)d_in[1];   // [1,160,160,4]
    const float* w   = (const float*)d_in[2];   // [8,8,4,64]
    float* out = (float*)d_out;                 // [1,160,160,4]

    argmax_rel_tile<<<TI * TI, 256, 0, stream>>>(rel, x, w, out);
}

// Round 5
// 16.717 us; speedup vs baseline: 1.5040x; 1.5040x over previous
//
#include <hip/hip_runtime.h>

// Problem constants (fixed by setup_inputs shapes)
#define HOUT 39
#define WOUT 39
#define COUT 64
#define HIN  160
#define WIN  160
#define CIN  4
#define F    8
#define S    4

// Block = one output position (i,j); 4 waves split the 256-element patch
// (k = (px*8+py)*4+pc) into 4 contiguous segments of 64; lane = channel c.
//
// VMEM-slim scan: the 64 x-values of a wave's k-window are loaded ONCE,
// coalesced, into lane k's register; the unrolled loop broadcasts them via
// v_readlane (literal lane index -> SALU, SGPR operand folds into v_mul).
// Per wave: 65 VMEM loads instead of 128. w reads stay coalesced over lane=c.
// Argmax: 4 independent 16-long chains (ILP), merged ascending-k with strict >
// (first-occurrence ties, matching jnp.argmax), cross-wave merge via LDS,
// wave 0 scatters with atomicAdd into the memset-zeroed output.
__global__ __launch_bounds__(256) void argmax_rel_kernel(
    const float* __restrict__ rel,   // [39,39,64]
    const float* __restrict__ x,     // [160,160,4]
    const float* __restrict__ w,     // [8,8,4,64] flat: [k][c]
    float* __restrict__ out)         // [160,160,4], pre-zeroed
{
    const int ij = blockIdx.x;                  // 0..1520
    const int i  = ij / WOUT;
    const int j  = ij - i * WOUT;
    const int wv = threadIdx.x >> 6;            // wave -> k in [wv*64, wv*64+64)
    const int c  = threadIdx.x & 63;

    // hoisted: relevance for this (i,j,c) — used by wave 0 after the merge
    const float r = rel[ij * COUT + c];

    const float* xp   = x + ((S * i) * WIN + (S * j)) * CIN;  // patch origin
    const int    kb   = wv * 64;                // patch rows px = 2wv, 2wv+1
    const float* rowb = xp + (2 * wv) * (WIN * CIN);

    // lane q holds x for k = kb+q: q<32 -> row0[q], q>=32 -> row1[q-32]
    const float xv    = (c < 32) ? rowb[c] : rowb[WIN * CIN + (c - 32)];
    const int   xbits = __float_as_int(xv);

    const float* wp = w + kb * COUT + c;        // coalesced over lanes

    float m0 = -__builtin_inff(), m1 = m0, m2 = m0, m3 = m0;
    int   a0 = kb, a1 = kb + 16, a2 = kb + 32, a3 = kb + 48;

    #pragma unroll
    for (int t = 0; t < 16; ++t) {
        const float x0 = __int_as_float(__builtin_amdgcn_readlane(xbits, t));
        const float x1 = __int_as_float(__builtin_amdgcn_readlane(xbits, t + 16));
        const float x2 = __int_as_float(__builtin_amdgcn_readlane(xbits, t + 32));
        const float x3 = __int_as_float(__builtin_amdgcn_readlane(xbits, t + 48));
        const float p0 = x0 * wp[(t)      * COUT];
        const float p1 = x1 * wp[(t + 16) * COUT];
        const float p2 = x2 * wp[(t + 32) * COUT];
        const float p3 = x3 * wp[(t + 48) * COUT];
        if (p0 > m0) { m0 = p0; a0 = kb + t; }
        if (p1 > m1) { m1 = p1; a1 = kb + 16 + t; }
        if (p2 > m2) { m2 = p2; a2 = kb + 32 + t; }
        if (p3 > m3) { m3 = p3; a3 = kb + 48 + t; }
    }

    // merge 4 chains, ascending k, strict > keeps earliest k on ties
    float m = m0; int a = a0;
    if (m1 > m) { m = m1; a = a1; }
    if (m2 > m) { m = m2; a = a2; }
    if (m3 > m) { m = m3; a = a3; }

    __shared__ float lm[4][COUT];
    __shared__ int   la[4][COUT];
    lm[wv][c] = m;
    la[wv][c] = a;
    __syncthreads();

    if (wv == 0) {
        float bm = lm[0][c]; int ba = la[0][c];
        #pragma unroll
        for (int s = 1; s < 4; ++s) {            // ascending k segments
            const float sm = lm[s][c];
            if (sm > bm) { bm = sm; ba = la[s][c]; }
        }
        // ba = (px*8+py)*4+pc ; flat output index
        const int px_  = ba >> 5;               // patch row
        const int rem  = ba & 31;               // py*4+pc
        const int gx   = S * i + px_;
        const int flat = gx * (WIN * CIN) + (S * j) * CIN + rem;

        atomicAdd(out + flat, r);
    }
}

extern "C" void kernel_launch(void* const* d_in, const int* in_sizes, int n_in,
                              void* d_out, int out_size, void* d_ws, size_t ws_size,
                              hipStream_t stream) {
    const float* rel = (const float*)d_in[0];   // [1,39,39,64]
    const float* x   = (const float*)d_in[1];   // [1,160,160,4]
    const float* w   = (const float*)d_in[2];   // [8,8,4,64]
    float* out = (float*)d_out;                 // [1,160,160,4]

    // Output is scatter-add target: must start at zero every call.
    hipMemsetAsync(out, 0, (size_t)out_size * sizeof(float), stream);

    argmax_rel_kernel<<<HOUT * WOUT, 256, 0, stream>>>(rel, x, w, out);
}